// Round 7
// baseline (428.862 us; speedup 1.0000x reference)
//
#include <hip/hip_runtime.h>
#include <hip/hip_bf16.h>

// Problem sizes (fixed by the reference)
#define N_NODES 10000
#define N_EDGES 160000

// ---------------------------------------------------------------------------
// Workspace layout (bytes) — fixed part ~11.6 MB; `mix` takes the rest and is
// chunked to whatever ws_size allows (adaptive, deterministic per call).
// ---------------------------------------------------------------------------
#define OFF_OFFSETS  40064
#define OFF_CURSORS  80128
#define OFF_ORDER    120192
#define OFF_Y        760320
#define OFF_SSORT    11000320
#define OFF_MIX      11640320

// ---------------- CSR build ----------------
__global__ void khist(const int* __restrict__ recv, int* __restrict__ counts) {
    int e = blockIdx.x * 256 + threadIdx.x;
    atomicAdd(&counts[recv[e]], 1);
}

// 1024-thread shuffle scan: thread t serially scans nodes [t*10, t*10+10),
// wave-level shuffle scan of thread sums, 16 wave totals combined in LDS.
__global__ __launch_bounds__(1024) void kscan(const int* __restrict__ counts,
                                              int* __restrict__ offsets,
                                              int* __restrict__ cursors) {
    __shared__ int wsum[16];
    __shared__ int wpre[16];
    const int tid  = threadIdx.x;
    const int lane = tid & 63;
    const int wv   = tid >> 6;
    const int base = tid * 10;                 // 1024*10 = 10240 >= N_NODES
    int v[10];
    int s = 0;
    #pragma unroll
    for (int j = 0; j < 10; ++j) {
        int i = base + j;
        v[j] = (i < N_NODES) ? counts[i] : 0;
        s += v[j];
    }
    int pre = s;                                // inclusive wave scan
    #pragma unroll
    for (int off = 1; off < 64; off <<= 1) {
        int t = __shfl_up(pre, off);
        if (lane >= off) pre += t;
    }
    if (lane == 63) wsum[wv] = pre;
    __syncthreads();
    if (wv == 0 && lane < 16) {
        int x = wsum[lane];
        int p = x;
        #pragma unroll
        for (int off = 1; off < 16; off <<= 1) {
            int t = __shfl_up(p, off);
            if (lane >= off) p += t;
        }
        wpre[lane] = p - x;                     // exclusive wave prefix
    }
    __syncthreads();
    int excl = wpre[wv] + pre - s;              // exclusive prefix for this thread
    #pragma unroll
    for (int j = 0; j < 10; ++j) {
        int i = base + j;
        if (i < N_NODES) { offsets[i] = excl; cursors[i] = excl; }
        excl += v[j];
    }
}

// ---------------- fused CSR-order + sender permute + spherical harmonics --------
__global__ void kprep(const float* __restrict__ vec, const int* __restrict__ senders,
                      const int* __restrict__ recv, int* __restrict__ cursors,
                      int* __restrict__ order, float* __restrict__ yw,
                      int* __restrict__ ssort) {
    int e = blockIdx.x * 256 + threadIdx.x;
    int r = recv[e];
    int p = atomicAdd(&cursors[r], 1);
    order[p] = e;
    ssort[p] = senders[e];

    float x = vec[e * 3 + 0], y = vec[e * 3 + 1], z = vec[e * 3 + 2];
    float nrm = sqrtf(x * x + y * y + z * z);
    float d = 1.f / (nrm + 1e-12f);
    x *= d; y *= d; z *= d;
    const float s3  = 1.7320508075688772f;
    const float s5  = 2.2360679774997896f;
    const float s15 = 3.8729833462074170f;
    const float c33 = 2.0916500663351889f;   // sqrt(35/8)
    const float c32 = 10.246950765959598f;   // sqrt(105)
    const float c31 = 1.6201851746019651f;   // sqrt(21/8)
    const float c30 = 1.3228756555322954f;   // 0.5*sqrt(7)
    float x2 = x * x, y2 = y * y, z2 = z * z;
    float4 a, b, c, dd;
    a.x = s3 * y;  a.y = s3 * z;  a.z = s3 * x;           // Y1
    a.w = s15 * x * y;                                     // Y2[0]
    b.x = s15 * y * z;
    b.y = 0.5f * s5 * (3.f * z2 - 1.f);
    b.z = s15 * x * z;
    b.w = 0.5f * s15 * (x2 - y2);
    c.x = c33 * y * (3.f * x2 - y2);                       // Y3
    c.y = c32 * x * y * z;
    c.z = c31 * y * (5.f * z2 - 1.f);
    c.w = c30 * z * (5.f * z2 - 3.f);
    dd.x = c31 * x * (5.f * z2 - 1.f);
    dd.y = 0.5f * c32 * z * (x2 - y2);
    dd.z = c33 * x * (x2 - 3.f * y2);
    dd.w = 0.f;
    float4* yp = reinterpret_cast<float4*>(yw + (size_t)p * 16);
    yp[0] = a; yp[1] = b; yp[2] = c; yp[3] = dd;
}

// ---------------- fused 4-layer radial MLP: lane = edge, weights via SGPR -------
// 64 threads/block = 1 wave = 64 edges. Each lane owns one edge's full channel
// vector: acc[64] in VGPRs (all indices static). Between layers the vector is
// staged in a lane-private LDS COLUMN h[k*65 + lane] (pad 65 -> bank (k+lane)%32,
// 2-way aliasing = free). Weight reads W[k*64+i] are wave-uniform -> compiler
// scalarizes to s_load + SGPR operand of v_fmac: ZERO vector-memory weight
// traffic (this is the fix for round-6's 9.8 GB FETCH_SIZE).
__device__ __forceinline__ float silu(float v) {
    return v / (1.f + __expf(-v));
}

// acc = h_col @ W  (h read from LDS column, k rolled with 1-ahead prefetch)
__device__ __forceinline__ void fc64(const float* __restrict__ W, int ldw,
                                     const float* __restrict__ hl, int lane,
                                     float* __restrict__ acc) {
    #pragma unroll
    for (int i = 0; i < 64; ++i) acc[i] = 0.f;
    float hk = hl[lane];                      // k = 0
    #pragma unroll 1
    for (int k = 0; k < 64; ++k) {
        const float hcur = hk;
        hk = hl[(k + 1) * 65 + lane];         // prefetch (k=63 reads pad row)
        const float* wr = W + (size_t)k * ldw;
        #pragma unroll
        for (int i = 0; i < 64; ++i)
            acc[i] = fmaf(hcur, wr[i], acc[i]);   // wr[i] uniform -> s_load/SGPR
    }
}

__global__ __launch_bounds__(64) void kmlp(const float* __restrict__ radial,
                                           const int* __restrict__ order,
                                           const float* __restrict__ w1,
                                           const float* __restrict__ w2,
                                           const float* __restrict__ w3,
                                           const float* __restrict__ w4,
                                           float* __restrict__ mix, int clo) {
    __shared__ float h[65 * 65];              // [k][lane] pad 65 (+1 prefetch row)
    const int lane = threadIdx.x;
    const int pb   = clo + blockIdx.x * 64;
    const int eid  = order[pb + lane];

    float acc[64];

    // ---- layer 1 (K=8): silu((r @ w1) / sqrt(8)) -> h column
    {
        const float* rp = radial + (size_t)eid * 8;
        float4 t0 = *reinterpret_cast<const float4*>(rp);
        float4 t1 = *reinterpret_cast<const float4*>(rp + 4);
        float r[8] = {t0.x, t0.y, t0.z, t0.w, t1.x, t1.y, t1.z, t1.w};
        #pragma unroll
        for (int i = 0; i < 64; ++i) acc[i] = 0.f;
        #pragma unroll
        for (int k = 0; k < 8; ++k) {
            const float* wr = w1 + k * 64;
            #pragma unroll
            for (int i = 0; i < 64; ++i)
                acc[i] = fmaf(r[k], wr[i], acc[i]);
        }
        #pragma unroll
        for (int i = 0; i < 64; ++i)
            h[i * 65 + lane] = silu(acc[i] * 0.35355339059327373f);
    }

    // ---- layer 2: silu((h @ w2)/8) -> h (lane-private column, in place)
    fc64(w2, 64, h, lane, acc);
    #pragma unroll
    for (int i = 0; i < 64; ++i) h[i * 65 + lane] = silu(acc[i] * 0.125f);

    // ---- layer 3: silu((h @ w3)/8) -> h
    fc64(w3, 64, h, lane, acc);
    #pragma unroll
    for (int i = 0; i < 64; ++i) h[i * 65 + lane] = silu(acc[i] * 0.125f);

    // ---- layer 4: (h @ w4)/8 -> mix row (lane-contiguous, full-line writes)
    float* gout = mix + (size_t)(blockIdx.x * 64 + lane) * 256;   // chunk-relative
    #pragma unroll 1
    for (int c = 0; c < 4; ++c) {
        fc64(w4 + c * 64, 256, h, lane, acc);
        #pragma unroll
        for (int q = 0; q < 16; ++q) {
            float4 o;
            o.x = acc[4 * q + 0] * 0.125f;
            o.y = acc[4 * q + 1] * 0.125f;
            o.z = acc[4 * q + 2] * 0.125f;
            o.w = acc[4 * q + 3] * 0.125f;
            *reinterpret_cast<float4*>(gout + c * 64 + 4 * q) = o;
        }
    }
}

// ---------------- per-node gather/accumulate (sequential mix/yw/ssort reads) ----
__global__ __launch_bounds__(256) void kgather(const float* __restrict__ mix,
                                               const float* __restrict__ yw,
                                               const int* __restrict__ ssort,
                                               const float* __restrict__ node_feats,
                                               const int* __restrict__ offsets,
                                               const int* __restrict__ counts,
                                               float* __restrict__ out,
                                               int clo, int chi) {
    __shared__ float so[4][1024];
    const int lane = threadIdx.x & 63;
    const int wv   = threadIdx.x >> 6;
    const int n    = blockIdx.x * 4 + wv;   // grid is exactly N_NODES/4

    const int start = offsets[n];
    const int cnt   = counts[n];
    const int end   = start + cnt;
    const int s0    = (start > clo) ? start : clo;
    const int s1    = (end < chi) ? end : chi;

    float a0 = 0.f;
    float a1[3] = {0.f, 0.f, 0.f};
    float a2[5] = {0.f, 0.f, 0.f, 0.f, 0.f};
    float a3[7] = {0.f, 0.f, 0.f, 0.f, 0.f, 0.f, 0.f};

    int i = s0;
    for (; i + 2 <= s1; i += 2) {
        const int sA = ssort[i];
        const int sB = ssort[i + 1];
        const float* mpA = mix + (size_t)(i - clo) * 256;
        const float* mpB = mpA + 256;
        const float fA = node_feats[sA * 64 + lane];
        const float fB = node_feats[sB * 64 + lane];
        const float4* ypA = reinterpret_cast<const float4*>(yw + (size_t)i * 16);
        const float4* ypB = ypA + 4;
        const float4 yaA = ypA[0], ybA = ypA[1], ycA = ypA[2], ydA = ypA[3];
        const float4 yaB = ypB[0], ybB = ypB[1], ycB = ypB[2], ydB = ypB[3];
        const float t0A = fA * mpA[lane],       t0B = fB * mpB[lane];
        const float t1A = fA * mpA[64 + lane],  t1B = fB * mpB[64 + lane];
        const float t2A = fA * mpA[128 + lane], t2B = fB * mpB[128 + lane];
        const float t3A = fA * mpA[192 + lane], t3B = fB * mpB[192 + lane];
        a0 += t0A + t0B;
        a1[0] += t1A * yaA.x + t1B * yaB.x;
        a1[1] += t1A * yaA.y + t1B * yaB.y;
        a1[2] += t1A * yaA.z + t1B * yaB.z;
        a2[0] += t2A * yaA.w + t2B * yaB.w;
        a2[1] += t2A * ybA.x + t2B * ybB.x;
        a2[2] += t2A * ybA.y + t2B * ybB.y;
        a2[3] += t2A * ybA.z + t2B * ybB.z;
        a2[4] += t2A * ybA.w + t2B * ybB.w;
        a3[0] += t3A * ycA.x + t3B * ycB.x;
        a3[1] += t3A * ycA.y + t3B * ycB.y;
        a3[2] += t3A * ycA.z + t3B * ycB.z;
        a3[3] += t3A * ycA.w + t3B * ycB.w;
        a3[4] += t3A * ydA.x + t3B * ydB.x;
        a3[5] += t3A * ydA.y + t3B * ydB.y;
        a3[6] += t3A * ydA.z + t3B * ydB.z;
    }
    if (i < s1) {
        const int sA = ssort[i];
        const float* mpA = mix + (size_t)(i - clo) * 256;
        const float fA = node_feats[sA * 64 + lane];
        const float4* ypA = reinterpret_cast<const float4*>(yw + (size_t)i * 16);
        const float4 yaA = ypA[0], ybA = ypA[1], ycA = ypA[2], ydA = ypA[3];
        const float t0A = fA * mpA[lane];
        const float t1A = fA * mpA[64 + lane];
        const float t2A = fA * mpA[128 + lane];
        const float t3A = fA * mpA[192 + lane];
        a0 += t0A;
        a1[0] += t1A * yaA.x; a1[1] += t1A * yaA.y; a1[2] += t1A * yaA.z;
        a2[0] += t2A * yaA.w; a2[1] += t2A * ybA.x; a2[2] += t2A * ybA.y;
        a2[3] += t2A * ybA.z; a2[4] += t2A * ybA.w;
        a3[0] += t3A * ycA.x; a3[1] += t3A * ycA.y; a3[2] += t3A * ycA.z;
        a3[3] += t3A * ycA.w; a3[4] += t3A * ydA.x; a3[5] += t3A * ydA.y;
        a3[6] += t3A * ydA.z;
    }

    // stage irrep-strided layout in LDS (wave-private), then coalesced store
    so[wv][lane] = a0;
    #pragma unroll
    for (int j = 0; j < 3; ++j) so[wv][64  + lane * 3 + j] = a1[j];
    #pragma unroll
    for (int j = 0; j < 5; ++j) so[wv][256 + lane * 5 + j] = a2[j];
    #pragma unroll
    for (int j = 0; j < 7; ++j) so[wv][576 + lane * 7 + j] = a3[j];

    float* op = out + (size_t)n * 1024;
    if (start >= clo) {           // chunk holds the node's first edge: store
        #pragma unroll
        for (int k = 0; k < 16; ++k)
            op[k * 64 + lane] = so[wv][k * 64 + lane] * 0.25f;   // 1/sqrt(16)
    } else if (s1 > s0) {         // continuation chunk: accumulate
        #pragma unroll
        for (int k = 0; k < 16; ++k)
            op[k * 64 + lane] += so[wv][k * 64 + lane] * 0.25f;
    }
}

// ---------------- launch ----------------
extern "C" void kernel_launch(void* const* d_in, const int* in_sizes, int n_in,
                              void* d_out, int out_size, void* d_ws, size_t ws_size,
                              hipStream_t stream) {
    const float* vectors    = (const float*)d_in[0];
    const float* node_feats = (const float*)d_in[1];
    const float* radial     = (const float*)d_in[2];
    const float* w1         = (const float*)d_in[3];
    const float* w2         = (const float*)d_in[4];
    const float* w3         = (const float*)d_in[5];
    const float* w4         = (const float*)d_in[6];
    const int*   senders    = (const int*)d_in[7];
    const int*   receivers  = (const int*)d_in[8];
    float*       out        = (float*)d_out;

    char* ws = (char*)d_ws;
    int*   counts  = (int*)(ws);
    int*   offsets = (int*)(ws + OFF_OFFSETS);
    int*   cursors = (int*)(ws + OFF_CURSORS);
    int*   order   = (int*)(ws + OFF_ORDER);
    float* yw      = (float*)(ws + OFF_Y);
    int*   ssort   = (int*)(ws + OFF_SSORT);
    float* mix     = (float*)(ws + OFF_MIX);

    // adaptive mix chunking from ws_size (constant per session -> graph-safe)
    size_t avail = (ws_size > (size_t)OFF_MIX) ? ws_size - (size_t)OFF_MIX : 0;
    long maxE = (long)(avail / (256 * 4));
    maxE -= maxE % 64;
    if (maxE < 64) maxE = 64;
    if (maxE > N_EDGES) maxE = N_EDGES;
    const int nch = (int)((N_EDGES + maxE - 1) / maxE);

    hipMemsetAsync(counts, 0, N_NODES * sizeof(int), stream);
    if (nch > 1)
        hipMemsetAsync(out, 0, (size_t)out_size * sizeof(float), stream);
    khist <<<N_EDGES / 256, 256, 0, stream>>>(receivers, counts);
    kscan <<<1, 1024, 0, stream>>>(counts, offsets, cursors);
    kprep <<<N_EDGES / 256, 256, 0, stream>>>(vectors, senders, receivers, cursors,
                                              order, yw, ssort);

    for (int c = 0; c < nch; ++c) {
        const int clo = (int)((long)c * maxE);
        const int chi = (int)(((long)clo + maxE < N_EDGES) ? clo + maxE : N_EDGES);
        kmlp   <<<(chi - clo) / 64, 64, 0, stream>>>(radial, order, w1, w2, w3, w4,
                                                     mix, clo);
        kgather<<<N_NODES / 4, 256, 0, stream>>>(mix, yw, ssort, node_feats,
                                                 offsets, counts, out, clo, chi);
    }
}

// Round 9
// 311.303 us; speedup vs baseline: 1.3776x; 1.3776x over previous
//
#include <hip/hip_runtime.h>
#include <hip/hip_bf16.h>

// Problem sizes (fixed by the reference)
#define N_NODES 10000
#define N_EDGES 160000

// ---------------------------------------------------------------------------
// Workspace layout (bytes) — fixed part ~11.6 MB; `mix` takes the rest and is
// chunked to whatever ws_size allows (adaptive, deterministic per call).
// ---------------------------------------------------------------------------
#define OFF_OFFSETS  40064
#define OFF_CURSORS  80128
#define OFF_ORDER    120192
#define OFF_Y        760320
#define OFF_SSORT    11000320
#define OFF_MIX      11640320

// ---------------- CSR build ----------------
__global__ void khist(const int* __restrict__ recv, int* __restrict__ counts) {
    int e = blockIdx.x * 256 + threadIdx.x;
    atomicAdd(&counts[recv[e]], 1);
}

// 1024-thread shuffle scan: thread t serially scans nodes [t*10, t*10+10),
// wave-level shuffle scan of thread sums, 16 wave totals combined in LDS.
__global__ __launch_bounds__(1024) void kscan(const int* __restrict__ counts,
                                              int* __restrict__ offsets,
                                              int* __restrict__ cursors) {
    __shared__ int wsum[16];
    __shared__ int wpre[16];
    const int tid  = threadIdx.x;
    const int lane = tid & 63;
    const int wv   = tid >> 6;
    const int base = tid * 10;                 // 1024*10 = 10240 >= N_NODES
    int v[10];
    int s = 0;
    #pragma unroll
    for (int j = 0; j < 10; ++j) {
        int i = base + j;
        v[j] = (i < N_NODES) ? counts[i] : 0;
        s += v[j];
    }
    int pre = s;                                // inclusive wave scan
    #pragma unroll
    for (int off = 1; off < 64; off <<= 1) {
        int t = __shfl_up(pre, off);
        if (lane >= off) pre += t;
    }
    if (lane == 63) wsum[wv] = pre;
    __syncthreads();
    if (wv == 0 && lane < 16) {
        int x = wsum[lane];
        int p = x;
        #pragma unroll
        for (int off = 1; off < 16; off <<= 1) {
            int t = __shfl_up(p, off);
            if (lane >= off) p += t;
        }
        wpre[lane] = p - x;                     // exclusive wave prefix
    }
    __syncthreads();
    int excl = wpre[wv] + pre - s;              // exclusive prefix for this thread
    #pragma unroll
    for (int j = 0; j < 10; ++j) {
        int i = base + j;
        if (i < N_NODES) { offsets[i] = excl; cursors[i] = excl; }
        excl += v[j];
    }
}

// ---------------- fused CSR-order + sender permute + spherical harmonics --------
__global__ void kprep(const float* __restrict__ vec, const int* __restrict__ senders,
                      const int* __restrict__ recv, int* __restrict__ cursors,
                      int* __restrict__ order, float* __restrict__ yw,
                      int* __restrict__ ssort) {
    int e = blockIdx.x * 256 + threadIdx.x;
    int r = recv[e];
    int p = atomicAdd(&cursors[r], 1);
    order[p] = e;
    ssort[p] = senders[e];

    float x = vec[e * 3 + 0], y = vec[e * 3 + 1], z = vec[e * 3 + 2];
    float nrm = sqrtf(x * x + y * y + z * z);
    float d = 1.f / (nrm + 1e-12f);
    x *= d; y *= d; z *= d;
    const float s3  = 1.7320508075688772f;
    const float s5  = 2.2360679774997896f;
    const float s15 = 3.8729833462074170f;
    const float c33 = 2.0916500663351889f;   // sqrt(35/8)
    const float c32 = 10.246950765959598f;   // sqrt(105)
    const float c31 = 1.6201851746019651f;   // sqrt(21/8)
    const float c30 = 1.3228756555322954f;   // 0.5*sqrt(7)
    float x2 = x * x, y2 = y * y, z2 = z * z;
    float4 a, b, c, dd;
    a.x = s3 * y;  a.y = s3 * z;  a.z = s3 * x;           // Y1
    a.w = s15 * x * y;                                     // Y2[0]
    b.x = s15 * y * z;
    b.y = 0.5f * s5 * (3.f * z2 - 1.f);
    b.z = s15 * x * z;
    b.w = 0.5f * s15 * (x2 - y2);
    c.x = c33 * y * (3.f * x2 - y2);                       // Y3
    c.y = c32 * x * y * z;
    c.z = c31 * y * (5.f * z2 - 1.f);
    c.w = c30 * z * (5.f * z2 - 3.f);
    dd.x = c31 * x * (5.f * z2 - 1.f);
    dd.y = 0.5f * c32 * z * (x2 - y2);
    dd.z = c33 * x * (x2 - 3.f * y2);
    dd.w = 0.f;
    float4* yp = reinterpret_cast<float4*>(yw + (size_t)p * 16);
    yp[0] = a; yp[1] = b; yp[2] = c; yp[3] = dd;
}

// ---------------- fused 4-layer radial MLP, 8x8 register tile -------------------
// 128-thread blocks = 2 waves; each wave owns 64 edges and a PRIVATE 16 KB h
// buffer (no barriers anywhere). Lane = (le in [0,8)) x (ln in [0,8)); lane
// owns acc[8 edges][8 channels] — weight bytes amortize over 8 edges (2x round
// 4/6), acts over 8 channels. Acts: LDS, XOR-quad-swizzled (quad' = quad^le),
// 8-distinct-address broadcast reads (conflict-free), updated IN-PLACE per
// layer (all reads precede writes in per-wave program order + compiler fence).
// Weights: streamed from global via vmem (L1-resident; now ~balanced with VALU).
#define MTILE 64                      // edges per wave
#define WPB   2                       // waves per block
#define BTILE (MTILE * WPB)           // 128 edges per block

__device__ __forceinline__ float silu(float v) {
    return v / (1.f + __expf(-v));
}

template<bool ACT, bool TO_LDS>
__device__ __forceinline__ void layer8x8(float* buf,                     // LDS [64][64] swizzled
                                         const float* __restrict__ W,    // global [64][ldw] (pre-offset by chunk)
                                         int ldw, float scale,
                                         float* __restrict__ gout,       // global (!TO_LDS), pre-offset
                                         int le, int ln) {
    float acc[8][8];
    #pragma unroll
    for (int j = 0; j < 8; ++j)
        #pragma unroll
        for (int i = 0; i < 8; ++i) acc[j][i] = 0.f;

    #pragma unroll 1
    for (int kq = 0; kq < 16; ++kq) {
        // weights first (vmem, long latency) — 8 x b128
        float w[4][8];
        #pragma unroll
        for (int kk = 0; kk < 4; ++kk) {
            const float* wr = W + (size_t)(kq * 4 + kk) * ldw + ln * 8;
            float4 t0 = *reinterpret_cast<const float4*>(wr);
            float4 t1 = *reinterpret_cast<const float4*>(wr + 4);
            w[kk][0] = t0.x; w[kk][1] = t0.y; w[kk][2] = t0.z; w[kk][3] = t0.w;
            w[kk][4] = t1.x; w[kk][5] = t1.y; w[kk][6] = t1.z; w[kk][7] = t1.w;
        }
        // acts — 8 x b128, 8 distinct addrs (le), broadcast to 8 ln-lanes each
        float4 a4[8];
        #pragma unroll
        for (int j = 0; j < 8; ++j)
            a4[j] = *reinterpret_cast<const float4*>(
                &buf[(le * 8 + j) * 64 + ((kq ^ le) << 2)]);
        #pragma unroll
        for (int j = 0; j < 8; ++j) {
            const float a0 = a4[j].x, a1 = a4[j].y, a2 = a4[j].z, a3 = a4[j].w;
            #pragma unroll
            for (int i = 0; i < 8; ++i) {
                acc[j][i] = fmaf(a0, w[0][i], acc[j][i]);
                acc[j][i] = fmaf(a1, w[1][i], acc[j][i]);
                acc[j][i] = fmaf(a2, w[2][i], acc[j][i]);
                acc[j][i] = fmaf(a3, w[3][i], acc[j][i]);
            }
        }
    }

    // fence: keep all LDS reads above, writes below (in-place update)
    asm volatile("" ::: "memory");

    #pragma unroll
    for (int j = 0; j < 8; ++j) {
        #pragma unroll
        for (int t = 0; t < 2; ++t) {
            float v0 = acc[j][t * 4 + 0] * scale;
            float v1 = acc[j][t * 4 + 1] * scale;
            float v2 = acc[j][t * 4 + 2] * scale;
            float v3 = acc[j][t * 4 + 3] * scale;
            float4 o;
            if (ACT) { o.x = silu(v0); o.y = silu(v1); o.z = silu(v2); o.w = silu(v3); }
            else     { o.x = v0; o.y = v1; o.z = v2; o.w = v3; }
            if (TO_LDS) {
                *reinterpret_cast<float4*>(
                    &buf[(le * 8 + j) * 64 + (((2 * ln + t) ^ le) << 2)]) = o;
            } else {
                *reinterpret_cast<float4*>(
                    &gout[(size_t)(le * 8 + j) * 256 + ln * 8 + t * 4]) = o;
            }
        }
    }
}

__global__ __launch_bounds__(128) void kmlp(const float* __restrict__ radial,
                                            const int* __restrict__ order,
                                            const float* __restrict__ w1,
                                            const float* __restrict__ w2,
                                            const float* __restrict__ w3,
                                            const float* __restrict__ w4,
                                            float* __restrict__ mix, int clo) {
    __shared__ float hs[WPB][MTILE * 64];    // 32 KB
    __shared__ float x0s[WPB][MTILE * 9];    // 4.5 KB (stride 9: conflict-free)
    const int tid  = threadIdx.x;
    const int lane = tid & 63;
    const int wv   = tid >> 6;
    const int ln   = lane & 7;
    const int le   = lane >> 3;
    float* h  = hs[wv];                       // wave-private
    float* x0 = x0s[wv];
    const int tbase = blockIdx.x * BTILE + wv * MTILE;   // chunk-relative edge base
    const int pb    = clo + tbase;                        // global permuted position

    // stage radial: lane = edge (64 edges/wave), row stride 9
    {
        const int e = order[pb + lane];
        const float* rp = radial + (size_t)e * 8;
        float4 t0 = *reinterpret_cast<const float4*>(rp);
        float4 t1 = *reinterpret_cast<const float4*>(rp + 4);
        float* xr = x0 + lane * 9;
        xr[0] = t0.x; xr[1] = t0.y; xr[2] = t0.z; xr[3] = t0.w;
        xr[4] = t1.x; xr[5] = t1.y; xr[6] = t1.z; xr[7] = t1.w;
    }
    // x0 written and read by the same wave — per-wave LDS ordering, no barrier.

    // ---- layer 1 (K=8): silu((x0 @ w1)/sqrt8) -> h
    {
        float acc[8][8];
        #pragma unroll
        for (int j = 0; j < 8; ++j)
            #pragma unroll
            for (int i = 0; i < 8; ++i) acc[j][i] = 0.f;
        #pragma unroll
        for (int k = 0; k < 8; ++k) {
            const float* wr = w1 + k * 64 + ln * 8;
            float4 t0 = *reinterpret_cast<const float4*>(wr);
            float4 t1 = *reinterpret_cast<const float4*>(wr + 4);
            float w[8] = {t0.x, t0.y, t0.z, t0.w, t1.x, t1.y, t1.z, t1.w};
            float a[8];
            #pragma unroll
            for (int j = 0; j < 8; ++j) a[j] = x0[(le * 8 + j) * 9 + k];
            #pragma unroll
            for (int j = 0; j < 8; ++j)
                #pragma unroll
                for (int i = 0; i < 8; ++i)
                    acc[j][i] = fmaf(a[j], w[i], acc[j][i]);
        }
        #pragma unroll
        for (int j = 0; j < 8; ++j) {
            #pragma unroll
            for (int t = 0; t < 2; ++t) {
                float4 o;
                o.x = silu(acc[j][t * 4 + 0] * 0.35355339059327373f);
                o.y = silu(acc[j][t * 4 + 1] * 0.35355339059327373f);
                o.z = silu(acc[j][t * 4 + 2] * 0.35355339059327373f);
                o.w = silu(acc[j][t * 4 + 3] * 0.35355339059327373f);
                *reinterpret_cast<float4*>(
                    &h[(le * 8 + j) * 64 + (((2 * ln + t) ^ le) << 2)]) = o;
            }
        }
    }

    // ---- layers 2,3: 64->64, silu, LDS in-place
    layer8x8<true, true>(h, w2, 64, 0.125f, nullptr, le, ln);
    layer8x8<true, true>(h, w3, 64, 0.125f, nullptr, le, ln);

    // ---- layer 4: 64->256 in 4 chunks, no act, -> mix (chunk-relative)
    float* gbase = mix + (size_t)tbase * 256;
    #pragma unroll 1
    for (int c = 0; c < 4; ++c)
        layer8x8<false, false>(h, w4 + c * 64, 256, 0.125f, gbase + c * 64, le, ln);
}

// ---------------- per-node gather/accumulate (sequential mix/yw/ssort reads) ----
__global__ __launch_bounds__(256) void kgather(const float* __restrict__ mix,
                                               const float* __restrict__ yw,
                                               const int* __restrict__ ssort,
                                               const float* __restrict__ node_feats,
                                               const int* __restrict__ offsets,
                                               const int* __restrict__ counts,
                                               float* __restrict__ out,
                                               int clo, int chi) {
    __shared__ float so[4][1024];
    const int lane = threadIdx.x & 63;
    const int wv   = threadIdx.x >> 6;
    const int n    = blockIdx.x * 4 + wv;   // grid is exactly N_NODES/4

    const int start = offsets[n];
    const int cnt   = counts[n];
    const int end   = start + cnt;
    const int s0    = (start > clo) ? start : clo;
    const int s1    = (end < chi) ? end : chi;

    float a0 = 0.f;
    float a1[3] = {0.f, 0.f, 0.f};
    float a2[5] = {0.f, 0.f, 0.f, 0.f, 0.f};
    float a3[7] = {0.f, 0.f, 0.f, 0.f, 0.f, 0.f, 0.f};

    int i = s0;
    for (; i + 2 <= s1; i += 2) {
        const int sA = ssort[i];
        const int sB = ssort[i + 1];
        const float* mpA = mix + (size_t)(i - clo) * 256;
        const float* mpB = mpA + 256;
        const float fA = node_feats[sA * 64 + lane];
        const float fB = node_feats[sB * 64 + lane];
        const float4* ypA = reinterpret_cast<const float4*>(yw + (size_t)i * 16);
        const float4* ypB = ypA + 4;
        const float4 yaA = ypA[0], ybA = ypA[1], ycA = ypA[2], ydA = ypA[3];
        const float4 yaB = ypB[0], ybB = ypB[1], ycB = ypB[2], ydB = ypB[3];
        const float t0A = fA * mpA[lane],       t0B = fB * mpB[lane];
        const float t1A = fA * mpA[64 + lane],  t1B = fB * mpB[64 + lane];
        const float t2A = fA * mpA[128 + lane], t2B = fB * mpB[128 + lane];
        const float t3A = fA * mpA[192 + lane], t3B = fB * mpB[192 + lane];
        a0 += t0A + t0B;
        a1[0] += t1A * yaA.x + t1B * yaB.x;
        a1[1] += t1A * yaA.y + t1B * yaB.y;
        a1[2] += t1A * yaA.z + t1B * yaB.z;
        a2[0] += t2A * yaA.w + t2B * yaB.w;
        a2[1] += t2A * ybA.x + t2B * ybB.x;
        a2[2] += t2A * ybA.y + t2B * ybB.y;
        a2[3] += t2A * ybA.z + t2B * ybB.z;
        a2[4] += t2A * ybA.w + t2B * ybB.w;
        a3[0] += t3A * ycA.x + t3B * ycB.x;
        a3[1] += t3A * ycA.y + t3B * ycB.y;
        a3[2] += t3A * ycA.z + t3B * ycB.z;
        a3[3] += t3A * ycA.w + t3B * ycB.w;
        a3[4] += t3A * ydA.x + t3B * ydB.x;
        a3[5] += t3A * ydA.y + t3B * ydB.y;
        a3[6] += t3A * ydA.z + t3B * ydB.z;
    }
    if (i < s1) {
        const int sA = ssort[i];
        const float* mpA = mix + (size_t)(i - clo) * 256;
        const float fA = node_feats[sA * 64 + lane];
        const float4* ypA = reinterpret_cast<const float4*>(yw + (size_t)i * 16);
        const float4 yaA = ypA[0], ybA = ypA[1], ycA = ypA[2], ydA = ypA[3];
        const float t0A = fA * mpA[lane];
        const float t1A = fA * mpA[64 + lane];
        const float t2A = fA * mpA[128 + lane];
        const float t3A = fA * mpA[192 + lane];
        a0 += t0A;
        a1[0] += t1A * yaA.x; a1[1] += t1A * yaA.y; a1[2] += t1A * yaA.z;
        a2[0] += t2A * yaA.w; a2[1] += t2A * ybA.x; a2[2] += t2A * ybA.y;
        a2[3] += t2A * ybA.z; a2[4] += t2A * ybA.w;
        a3[0] += t3A * ycA.x; a3[1] += t3A * ycA.y; a3[2] += t3A * ycA.z;
        a3[3] += t3A * ycA.w; a3[4] += t3A * ydA.x; a3[5] += t3A * ydA.y;
        a3[6] += t3A * ydA.z;
    }

    // stage irrep-strided layout in LDS (wave-private), then coalesced store
    so[wv][lane] = a0;
    #pragma unroll
    for (int j = 0; j < 3; ++j) so[wv][64  + lane * 3 + j] = a1[j];
    #pragma unroll
    for (int j = 0; j < 5; ++j) so[wv][256 + lane * 5 + j] = a2[j];
    #pragma unroll
    for (int j = 0; j < 7; ++j) so[wv][576 + lane * 7 + j] = a3[j];

    float* op = out + (size_t)n * 1024;
    if (start >= clo) {           // chunk holds the node's first edge: store
        #pragma unroll
        for (int k = 0; k < 16; ++k)
            op[k * 64 + lane] = so[wv][k * 64 + lane] * 0.25f;   // 1/sqrt(16)
    } else if (s1 > s0) {         // continuation chunk: accumulate
        #pragma unroll
        for (int k = 0; k < 16; ++k)
            op[k * 64 + lane] += so[wv][k * 64 + lane] * 0.25f;
    }
}

// ---------------- launch ----------------
extern "C" void kernel_launch(void* const* d_in, const int* in_sizes, int n_in,
                              void* d_out, int out_size, void* d_ws, size_t ws_size,
                              hipStream_t stream) {
    const float* vectors    = (const float*)d_in[0];
    const float* node_feats = (const float*)d_in[1];
    const float* radial     = (const float*)d_in[2];
    const float* w1         = (const float*)d_in[3];
    const float* w2         = (const float*)d_in[4];
    const float* w3         = (const float*)d_in[5];
    const float* w4         = (const float*)d_in[6];
    const int*   senders    = (const int*)d_in[7];
    const int*   receivers  = (const int*)d_in[8];
    float*       out        = (float*)d_out;

    char* ws = (char*)d_ws;
    int*   counts  = (int*)(ws);
    int*   offsets = (int*)(ws + OFF_OFFSETS);
    int*   cursors = (int*)(ws + OFF_CURSORS);
    int*   order   = (int*)(ws + OFF_ORDER);
    float* yw      = (float*)(ws + OFF_Y);
    int*   ssort   = (int*)(ws + OFF_SSORT);
    float* mix     = (float*)(ws + OFF_MIX);

    // adaptive mix chunking from ws_size (constant per session -> graph-safe)
    size_t avail = (ws_size > (size_t)OFF_MIX) ? ws_size - (size_t)OFF_MIX : 0;
    long maxE = (long)(avail / (256 * 4));
    maxE -= maxE % BTILE;
    if (maxE < BTILE) maxE = BTILE;
    if (maxE > N_EDGES) maxE = N_EDGES;
    const int nch = (int)((N_EDGES + maxE - 1) / maxE);

    hipMemsetAsync(counts, 0, N_NODES * sizeof(int), stream);
    if (nch > 1)
        hipMemsetAsync(out, 0, (size_t)out_size * sizeof(float), stream);
    khist <<<N_EDGES / 256, 256, 0, stream>>>(receivers, counts);
    kscan <<<1, 1024, 0, stream>>>(counts, offsets, cursors);
    kprep <<<N_EDGES / 256, 256, 0, stream>>>(vectors, senders, receivers, cursors,
                                              order, yw, ssort);

    for (int c = 0; c < nch; ++c) {
        const int clo = (int)((long)c * maxE);
        const int chi = (int)(((long)clo + maxE < N_EDGES) ? clo + maxE : N_EDGES);
        kmlp   <<<(chi - clo) / BTILE, 128, 0, stream>>>(radial, order, w1, w2, w3, w4,
                                                         mix, clo);
        kgather<<<N_NODES / 4, 256, 0, stream>>>(mix, yw, ssort, node_feats,
                                                 offsets, counts, out, clo, chi);
    }
}

// Round 10
// 303.106 us; speedup vs baseline: 1.4149x; 1.0270x over previous
//
#include <hip/hip_runtime.h>
#include <hip/hip_bf16.h>

// Problem sizes (fixed by the reference)
#define N_NODES 10000
#define N_EDGES 160000

// ---------------------------------------------------------------------------
// Workspace layout (bytes) — fixed part ~11.6 MB; `mix` takes the rest and is
// chunked to whatever ws_size allows (adaptive, deterministic per call).
// ---------------------------------------------------------------------------
#define OFF_OFFSETS  40064
#define OFF_CURSORS  80128
#define OFF_ORDER    120192
#define OFF_Y        760320
#define OFF_SSORT    11000320
#define OFF_MIX      11640320

// ---------------- CSR build ----------------
__global__ void khist(const int* __restrict__ recv, int* __restrict__ counts) {
    int e = blockIdx.x * 256 + threadIdx.x;
    atomicAdd(&counts[recv[e]], 1);
}

// 1024-thread shuffle scan: thread t serially scans nodes [t*10, t*10+10),
// wave-level shuffle scan of thread sums, 16 wave totals combined in LDS.
__global__ __launch_bounds__(1024) void kscan(const int* __restrict__ counts,
                                              int* __restrict__ offsets,
                                              int* __restrict__ cursors) {
    __shared__ int wsum[16];
    __shared__ int wpre[16];
    const int tid  = threadIdx.x;
    const int lane = tid & 63;
    const int wv   = tid >> 6;
    const int base = tid * 10;                 // 1024*10 = 10240 >= N_NODES
    int v[10];
    int s = 0;
    #pragma unroll
    for (int j = 0; j < 10; ++j) {
        int i = base + j;
        v[j] = (i < N_NODES) ? counts[i] : 0;
        s += v[j];
    }
    int pre = s;                                // inclusive wave scan
    #pragma unroll
    for (int off = 1; off < 64; off <<= 1) {
        int t = __shfl_up(pre, off);
        if (lane >= off) pre += t;
    }
    if (lane == 63) wsum[wv] = pre;
    __syncthreads();
    if (wv == 0 && lane < 16) {
        int x = wsum[lane];
        int p = x;
        #pragma unroll
        for (int off = 1; off < 16; off <<= 1) {
            int t = __shfl_up(p, off);
            if (lane >= off) p += t;
        }
        wpre[lane] = p - x;                     // exclusive wave prefix
    }
    __syncthreads();
    int excl = wpre[wv] + pre - s;              // exclusive prefix for this thread
    #pragma unroll
    for (int j = 0; j < 10; ++j) {
        int i = base + j;
        if (i < N_NODES) { offsets[i] = excl; cursors[i] = excl; }
        excl += v[j];
    }
}

// ---------------- fused CSR-order + sender permute + spherical harmonics --------
__global__ void kprep(const float* __restrict__ vec, const int* __restrict__ senders,
                      const int* __restrict__ recv, int* __restrict__ cursors,
                      int* __restrict__ order, float* __restrict__ yw,
                      int* __restrict__ ssort) {
    int e = blockIdx.x * 256 + threadIdx.x;
    int r = recv[e];
    int p = atomicAdd(&cursors[r], 1);
    order[p] = e;
    ssort[p] = senders[e];

    float x = vec[e * 3 + 0], y = vec[e * 3 + 1], z = vec[e * 3 + 2];
    float nrm = sqrtf(x * x + y * y + z * z);
    float d = 1.f / (nrm + 1e-12f);
    x *= d; y *= d; z *= d;
    const float s3  = 1.7320508075688772f;
    const float s5  = 2.2360679774997896f;
    const float s15 = 3.8729833462074170f;
    const float c33 = 2.0916500663351889f;   // sqrt(35/8)
    const float c32 = 10.246950765959598f;   // sqrt(105)
    const float c31 = 1.6201851746019651f;   // sqrt(21/8)
    const float c30 = 1.3228756555322954f;   // 0.5*sqrt(7)
    float x2 = x * x, y2 = y * y, z2 = z * z;
    float4 a, b, c, dd;
    a.x = s3 * y;  a.y = s3 * z;  a.z = s3 * x;           // Y1
    a.w = s15 * x * y;                                     // Y2[0]
    b.x = s15 * y * z;
    b.y = 0.5f * s5 * (3.f * z2 - 1.f);
    b.z = s15 * x * z;
    b.w = 0.5f * s15 * (x2 - y2);
    c.x = c33 * y * (3.f * x2 - y2);                       // Y3
    c.y = c32 * x * y * z;
    c.z = c31 * y * (5.f * z2 - 1.f);
    c.w = c30 * z * (5.f * z2 - 3.f);
    dd.x = c31 * x * (5.f * z2 - 1.f);
    dd.y = 0.5f * c32 * z * (x2 - y2);
    dd.z = c33 * x * (x2 - 3.f * y2);
    dd.w = 0.f;
    float4* yp = reinterpret_cast<float4*>(yw + (size_t)p * 16);
    yp[0] = a; yp[1] = b; yp[2] = c; yp[3] = dd;
}

// ---------------- fused 4-layer radial MLP, 8x8 tile, WEIGHTS FROM LDS ----------
// 128-thread blocks = 2 waves, 64 edges/wave. Lane = (le in [0,8)) x (ln in
// [0,8)); lane owns acc[8 edges][8 channels]. The round-4..9 plateau was the
// vmem DATA-RETURN bus: weight b128 loads carried 8x duplicated data (8 le
// groups, same address). Fix: stage each layer's weight panel (16 KB) into LDS
// once per block (unique data, cooperative), inner loop reads weights via
// ds_read_b128 — LDS broadcast is free, ln pattern is 2-way aliased (free).
// Acts: LDS h buffer, XOR-quad swizzle (quad' = quad^le), conflict-free,
// updated in place per layer (reads precede writes in per-wave program order
// + compiler fence). LDS 48 KB -> 3 blocks/CU; LDS/VALU co-critical.
#define MTILE 64                      // edges per wave
#define WPB   2                       // waves per block
#define BTILE (MTILE * WPB)           // 128 edges per block

__device__ __forceinline__ float silu(float v) {
    return v / (1.f + __expf(-v));
}

template<bool ACT, bool TO_LDS>
__device__ __forceinline__ void layer8x8(float* buf,                     // LDS h [64][64] swizzled
                                         const float* wlds,              // LDS weights [64][64]
                                         float scale,
                                         float* __restrict__ gout,       // global (!TO_LDS), pre-offset
                                         int le, int ln) {
    float acc[8][8];
    #pragma unroll
    for (int j = 0; j < 8; ++j)
        #pragma unroll
        for (int i = 0; i < 8; ++i) acc[j][i] = 0.f;

    #pragma unroll 2
    for (int kq = 0; kq < 16; ++kq) {
        // weights from LDS — 8 x ds_read_b128, 8 distinct addrs (ln), 2-way alias
        float w[4][8];
        #pragma unroll
        for (int kk = 0; kk < 4; ++kk) {
            const float* wr = wlds + (kq * 4 + kk) * 64 + ln * 8;
            float4 t0 = *reinterpret_cast<const float4*>(wr);
            float4 t1 = *reinterpret_cast<const float4*>(wr + 4);
            w[kk][0] = t0.x; w[kk][1] = t0.y; w[kk][2] = t0.z; w[kk][3] = t0.w;
            w[kk][4] = t1.x; w[kk][5] = t1.y; w[kk][6] = t1.z; w[kk][7] = t1.w;
        }
        // acts — 8 x ds_read_b128, 8 distinct addrs (le), conflict-free
        float4 a4[8];
        #pragma unroll
        for (int j = 0; j < 8; ++j)
            a4[j] = *reinterpret_cast<const float4*>(
                &buf[(le * 8 + j) * 64 + ((kq ^ le) << 2)]);
        #pragma unroll
        for (int j = 0; j < 8; ++j) {
            const float a0 = a4[j].x, a1 = a4[j].y, a2 = a4[j].z, a3 = a4[j].w;
            #pragma unroll
            for (int i = 0; i < 8; ++i) {
                acc[j][i] = fmaf(a0, w[0][i], acc[j][i]);
                acc[j][i] = fmaf(a1, w[1][i], acc[j][i]);
                acc[j][i] = fmaf(a2, w[2][i], acc[j][i]);
                acc[j][i] = fmaf(a3, w[3][i], acc[j][i]);
            }
        }
    }

    // fence: keep all LDS reads above, writes below (in-place h update)
    asm volatile("" ::: "memory");

    #pragma unroll
    for (int j = 0; j < 8; ++j) {
        #pragma unroll
        for (int t = 0; t < 2; ++t) {
            float v0 = acc[j][t * 4 + 0] * scale;
            float v1 = acc[j][t * 4 + 1] * scale;
            float v2 = acc[j][t * 4 + 2] * scale;
            float v3 = acc[j][t * 4 + 3] * scale;
            float4 o;
            if (ACT) { o.x = silu(v0); o.y = silu(v1); o.z = silu(v2); o.w = silu(v3); }
            else     { o.x = v0; o.y = v1; o.z = v2; o.w = v3; }
            if (TO_LDS) {
                *reinterpret_cast<float4*>(
                    &buf[(le * 8 + j) * 64 + (((2 * ln + t) ^ le) << 2)]) = o;
            } else {
                *reinterpret_cast<float4*>(
                    &gout[(size_t)(le * 8 + j) * 256 + ln * 8 + t * 4]) = o;
            }
        }
    }
}

__global__ __launch_bounds__(128) void kmlp(const float* __restrict__ radial,
                                            const int* __restrict__ order,
                                            const float* __restrict__ w1,
                                            const float* __restrict__ w2,
                                            const float* __restrict__ w3,
                                            const float* __restrict__ w4,
                                            float* __restrict__ mix, int clo) {
    __shared__ float hs[WPB][MTILE * 64];    // 32 KB (wave-private halves)
    __shared__ float wbuf[64 * 64];          // 16 KB weight panel (block-shared)
    const int tid  = threadIdx.x;
    const int lane = tid & 63;
    const int wv   = tid >> 6;
    const int ln   = lane & 7;
    const int le   = lane >> 3;
    float* h = hs[wv];
    const int tbase = blockIdx.x * BTILE + wv * MTILE;   // chunk-relative edge base
    const int pb    = clo + tbase;                        // global permuted position

    // ---- stage w2 panel (runs before layer1; barrier after layer1 covers it)
    {
        const float4* src = reinterpret_cast<const float4*>(w2);
        float4* dst = reinterpret_cast<float4*>(wbuf);
        #pragma unroll
        for (int r = 0; r < 8; ++r) dst[r * 128 + tid] = src[r * 128 + tid];
    }

    // ---- layer 1 (K=8): acts in registers (per-lane, 8 edges); w1 from global
    {
        float ax[8][8];
        #pragma unroll
        for (int j = 0; j < 8; ++j) {
            const int e = order[pb + le * 8 + j];
            const float* rp = radial + (size_t)e * 8;
            float4 t0 = *reinterpret_cast<const float4*>(rp);
            float4 t1 = *reinterpret_cast<const float4*>(rp + 4);
            ax[j][0] = t0.x; ax[j][1] = t0.y; ax[j][2] = t0.z; ax[j][3] = t0.w;
            ax[j][4] = t1.x; ax[j][5] = t1.y; ax[j][6] = t1.z; ax[j][7] = t1.w;
        }
        float acc[8][8];
        #pragma unroll
        for (int j = 0; j < 8; ++j)
            #pragma unroll
            for (int i = 0; i < 8; ++i) acc[j][i] = 0.f;
        #pragma unroll
        for (int k = 0; k < 8; ++k) {
            const float* wr = w1 + k * 64 + ln * 8;
            float4 t0 = *reinterpret_cast<const float4*>(wr);
            float4 t1 = *reinterpret_cast<const float4*>(wr + 4);
            float w[8] = {t0.x, t0.y, t0.z, t0.w, t1.x, t1.y, t1.z, t1.w};
            #pragma unroll
            for (int j = 0; j < 8; ++j)
                #pragma unroll
                for (int i = 0; i < 8; ++i)
                    acc[j][i] = fmaf(ax[j][k], w[i], acc[j][i]);
        }
        #pragma unroll
        for (int j = 0; j < 8; ++j) {
            #pragma unroll
            for (int t = 0; t < 2; ++t) {
                float4 o;
                o.x = silu(acc[j][t * 4 + 0] * 0.35355339059327373f);
                o.y = silu(acc[j][t * 4 + 1] * 0.35355339059327373f);
                o.z = silu(acc[j][t * 4 + 2] * 0.35355339059327373f);
                o.w = silu(acc[j][t * 4 + 3] * 0.35355339059327373f);
                *reinterpret_cast<float4*>(
                    &h[(le * 8 + j) * 64 + (((2 * ln + t) ^ le) << 2)]) = o;
            }
        }
    }
    __syncthreads();                                  // w2 staged, layer1 done

    // ---- layer 2: 64->64, silu, weights from LDS
    layer8x8<true, true>(h, wbuf, 0.125f, nullptr, le, ln);
    __syncthreads();                                  // all waves done with w2

    // ---- stage w3, layer 3
    {
        const float4* src = reinterpret_cast<const float4*>(w3);
        float4* dst = reinterpret_cast<float4*>(wbuf);
        #pragma unroll
        for (int r = 0; r < 8; ++r) dst[r * 128 + tid] = src[r * 128 + tid];
    }
    __syncthreads();
    layer8x8<true, true>(h, wbuf, 0.125f, nullptr, le, ln);
    __syncthreads();

    // ---- layer 4: 64->256 in 4 column chunks, each staged then consumed
    float* gbase = mix + (size_t)tbase * 256;
    #pragma unroll 1
    for (int c = 0; c < 4; ++c) {
        {   // stage w4[:, c*64 : c*64+64] -> wbuf (w4 row = 64 float4s)
            const float4* src = reinterpret_cast<const float4*>(w4);
            float4* dst = reinterpret_cast<float4*>(wbuf);
            #pragma unroll
            for (int r = 0; r < 8; ++r) {
                int idx = r * 128 + tid;
                int k = idx >> 4, q = idx & 15;
                dst[idx] = src[(size_t)k * 64 + c * 16 + q];
            }
        }
        __syncthreads();
        layer8x8<false, false>(h, wbuf, 0.125f, gbase + c * 64, le, ln);
        __syncthreads();
    }
}

// ---------------- per-node gather/accumulate (sequential mix/yw/ssort reads) ----
__global__ __launch_bounds__(256) void kgather(const float* __restrict__ mix,
                                               const float* __restrict__ yw,
                                               const int* __restrict__ ssort,
                                               const float* __restrict__ node_feats,
                                               const int* __restrict__ offsets,
                                               const int* __restrict__ counts,
                                               float* __restrict__ out,
                                               int clo, int chi) {
    __shared__ float so[4][1024];
    const int lane = threadIdx.x & 63;
    const int wv   = threadIdx.x >> 6;
    const int n    = blockIdx.x * 4 + wv;   // grid is exactly N_NODES/4

    const int start = offsets[n];
    const int cnt   = counts[n];
    const int end   = start + cnt;
    const int s0    = (start > clo) ? start : clo;
    const int s1    = (end < chi) ? end : chi;

    float a0 = 0.f;
    float a1[3] = {0.f, 0.f, 0.f};
    float a2[5] = {0.f, 0.f, 0.f, 0.f, 0.f};
    float a3[7] = {0.f, 0.f, 0.f, 0.f, 0.f, 0.f, 0.f};

    int i = s0;
    for (; i + 2 <= s1; i += 2) {
        const int sA = ssort[i];
        const int sB = ssort[i + 1];
        const float* mpA = mix + (size_t)(i - clo) * 256;
        const float* mpB = mpA + 256;
        const float fA = node_feats[sA * 64 + lane];
        const float fB = node_feats[sB * 64 + lane];
        const float4* ypA = reinterpret_cast<const float4*>(yw + (size_t)i * 16);
        const float4* ypB = ypA + 4;
        const float4 yaA = ypA[0], ybA = ypA[1], ycA = ypA[2], ydA = ypA[3];
        const float4 yaB = ypB[0], ybB = ypB[1], ycB = ypB[2], ydB = ypB[3];
        const float t0A = fA * mpA[lane],       t0B = fB * mpB[lane];
        const float t1A = fA * mpA[64 + lane],  t1B = fB * mpB[64 + lane];
        const float t2A = fA * mpA[128 + lane], t2B = fB * mpB[128 + lane];
        const float t3A = fA * mpA[192 + lane], t3B = fB * mpB[192 + lane];
        a0 += t0A + t0B;
        a1[0] += t1A * yaA.x + t1B * yaB.x;
        a1[1] += t1A * yaA.y + t1B * yaB.y;
        a1[2] += t1A * yaA.z + t1B * yaB.z;
        a2[0] += t2A * yaA.w + t2B * yaB.w;
        a2[1] += t2A * ybA.x + t2B * ybB.x;
        a2[2] += t2A * ybA.y + t2B * ybB.y;
        a2[3] += t2A * ybA.z + t2B * ybB.z;
        a2[4] += t2A * ybA.w + t2B * ybB.w;
        a3[0] += t3A * ycA.x + t3B * ycB.x;
        a3[1] += t3A * ycA.y + t3B * ycB.y;
        a3[2] += t3A * ycA.z + t3B * ycB.z;
        a3[3] += t3A * ycA.w + t3B * ycB.w;
        a3[4] += t3A * ydA.x + t3B * ydB.x;
        a3[5] += t3A * ydA.y + t3B * ydB.y;
        a3[6] += t3A * ydA.z + t3B * ydB.z;
    }
    if (i < s1) {
        const int sA = ssort[i];
        const float* mpA = mix + (size_t)(i - clo) * 256;
        const float fA = node_feats[sA * 64 + lane];
        const float4* ypA = reinterpret_cast<const float4*>(yw + (size_t)i * 16);
        const float4 yaA = ypA[0], ybA = ypA[1], ycA = ypA[2], ydA = ypA[3];
        const float t0A = fA * mpA[lane];
        const float t1A = fA * mpA[64 + lane];
        const float t2A = fA * mpA[128 + lane];
        const float t3A = fA * mpA[192 + lane];
        a0 += t0A;
        a1[0] += t1A * yaA.x; a1[1] += t1A * yaA.y; a1[2] += t1A * yaA.z;
        a2[0] += t2A * yaA.w; a2[1] += t2A * ybA.x; a2[2] += t2A * ybA.y;
        a2[3] += t2A * ybA.z; a2[4] += t2A * ybA.w;
        a3[0] += t3A * ycA.x; a3[1] += t3A * ycA.y; a3[2] += t3A * ycA.z;
        a3[3] += t3A * ycA.w; a3[4] += t3A * ydA.x; a3[5] += t3A * ydA.y;
        a3[6] += t3A * ydA.z;
    }

    // stage irrep-strided layout in LDS (wave-private), then coalesced store
    so[wv][lane] = a0;
    #pragma unroll
    for (int j = 0; j < 3; ++j) so[wv][64  + lane * 3 + j] = a1[j];
    #pragma unroll
    for (int j = 0; j < 5; ++j) so[wv][256 + lane * 5 + j] = a2[j];
    #pragma unroll
    for (int j = 0; j < 7; ++j) so[wv][576 + lane * 7 + j] = a3[j];

    float* op = out + (size_t)n * 1024;
    if (start >= clo) {           // chunk holds the node's first edge: store
        #pragma unroll
        for (int k = 0; k < 16; ++k)
            op[k * 64 + lane] = so[wv][k * 64 + lane] * 0.25f;   // 1/sqrt(16)
    } else if (s1 > s0) {         // continuation chunk: accumulate
        #pragma unroll
        for (int k = 0; k < 16; ++k)
            op[k * 64 + lane] += so[wv][k * 64 + lane] * 0.25f;
    }
}

// ---------------- launch ----------------
extern "C" void kernel_launch(void* const* d_in, const int* in_sizes, int n_in,
                              void* d_out, int out_size, void* d_ws, size_t ws_size,
                              hipStream_t stream) {
    const float* vectors    = (const float*)d_in[0];
    const float* node_feats = (const float*)d_in[1];
    const float* radial     = (const float*)d_in[2];
    const float* w1         = (const float*)d_in[3];
    const float* w2         = (const float*)d_in[4];
    const float* w3         = (const float*)d_in[5];
    const float* w4         = (const float*)d_in[6];
    const int*   senders    = (const int*)d_in[7];
    const int*   receivers  = (const int*)d_in[8];
    float*       out        = (float*)d_out;

    char* ws = (char*)d_ws;
    int*   counts  = (int*)(ws);
    int*   offsets = (int*)(ws + OFF_OFFSETS);
    int*   cursors = (int*)(ws + OFF_CURSORS);
    int*   order   = (int*)(ws + OFF_ORDER);
    float* yw      = (float*)(ws + OFF_Y);
    int*   ssort   = (int*)(ws + OFF_SSORT);
    float* mix     = (float*)(ws + OFF_MIX);

    // adaptive mix chunking from ws_size (constant per session -> graph-safe)
    size_t avail = (ws_size > (size_t)OFF_MIX) ? ws_size - (size_t)OFF_MIX : 0;
    long maxE = (long)(avail / (256 * 4));
    maxE -= maxE % BTILE;
    if (maxE < BTILE) maxE = BTILE;
    if (maxE > N_EDGES) maxE = N_EDGES;
    const int nch = (int)((N_EDGES + maxE - 1) / maxE);

    hipMemsetAsync(counts, 0, N_NODES * sizeof(int), stream);
    if (nch > 1)
        hipMemsetAsync(out, 0, (size_t)out_size * sizeof(float), stream);
    khist <<<N_EDGES / 256, 256, 0, stream>>>(receivers, counts);
    kscan <<<1, 1024, 0, stream>>>(counts, offsets, cursors);
    kprep <<<N_EDGES / 256, 256, 0, stream>>>(vectors, senders, receivers, cursors,
                                              order, yw, ssort);

    for (int c = 0; c < nch; ++c) {
        const int clo = (int)((long)c * maxE);
        const int chi = (int)(((long)clo + maxE < N_EDGES) ? clo + maxE : N_EDGES);
        kmlp   <<<(chi - clo) / BTILE, 128, 0, stream>>>(radial, order, w1, w2, w3, w4,
                                                         mix, clo);
        kgather<<<N_NODES / 4, 256, 0, stream>>>(mix, yw, ssort, node_feats,
                                                 offsets, counts, out, clo, chi);
    }
}

// Round 11
// 231.482 us; speedup vs baseline: 1.8527x; 1.3094x over previous
//
#include <hip/hip_runtime.h>
#include <hip/hip_bf16.h>

// Problem sizes (fixed by the reference)
#define N_NODES 10000
#define N_EDGES 160000

// ---------------------------------------------------------------------------
// Workspace layout (bytes)
// ---------------------------------------------------------------------------
#define OFF_OFFSETS  40064
#define OFF_CURSORS  80128
#define OFF_ORDER    120192
#define OFF_Y        760320
#define OFF_SSORT    11000320
#define OFF_WPK1     11640320   // 4nt*1ks*2pl*64*16B  = 8192
#define OFF_WPK2     11648512   // 4*2*2*64*16         = 16384
#define OFF_WPK3     11664896   // 16384
#define OFF_WPK4     11681280   // 16*2*2*64*16        = 65536
#define OFF_MIX      11746816

typedef __attribute__((ext_vector_type(8))) short short8;
typedef __attribute__((ext_vector_type(4))) float f32x4;

__device__ __forceinline__ unsigned short f2bf(float f) {   // RTNE fp32->bf16
    unsigned int u = __float_as_uint(f);
    u = (u + 0x7fffu + ((u >> 16) & 1u)) >> 16;
    return (unsigned short)u;
}
__device__ __forceinline__ float bf2f(unsigned short h) {
    return __uint_as_float(((unsigned int)h) << 16);
}
__device__ __forceinline__ float silu(float v) {
    return v / (1.f + __expf(-v));
}

// ---------------- CSR build ----------------
__global__ void khist(const int* __restrict__ recv, int* __restrict__ counts) {
    int e = blockIdx.x * 256 + threadIdx.x;
    atomicAdd(&counts[recv[e]], 1);
}

__global__ __launch_bounds__(1024) void kscan(const int* __restrict__ counts,
                                              int* __restrict__ offsets,
                                              int* __restrict__ cursors) {
    __shared__ int wsum[16];
    __shared__ int wpre[16];
    const int tid  = threadIdx.x;
    const int lane = tid & 63;
    const int wv   = tid >> 6;
    const int base = tid * 10;
    int v[10];
    int s = 0;
    #pragma unroll
    for (int j = 0; j < 10; ++j) {
        int i = base + j;
        v[j] = (i < N_NODES) ? counts[i] : 0;
        s += v[j];
    }
    int pre = s;
    #pragma unroll
    for (int off = 1; off < 64; off <<= 1) {
        int t = __shfl_up(pre, off);
        if (lane >= off) pre += t;
    }
    if (lane == 63) wsum[wv] = pre;
    __syncthreads();
    if (wv == 0 && lane < 16) {
        int x = wsum[lane];
        int p = x;
        #pragma unroll
        for (int off = 1; off < 16; off <<= 1) {
            int t = __shfl_up(p, off);
            if (lane >= off) p += t;
        }
        wpre[lane] = p - x;
    }
    __syncthreads();
    int excl = wpre[wv] + pre - s;
    #pragma unroll
    for (int j = 0; j < 10; ++j) {
        int i = base + j;
        if (i < N_NODES) { offsets[i] = excl; cursors[i] = excl; }
        excl += v[j];
    }
}

// ---------------- fused CSR-order + sender permute + spherical harmonics -------
__global__ void kprep(const float* __restrict__ vec, const int* __restrict__ senders,
                      const int* __restrict__ recv, int* __restrict__ cursors,
                      int* __restrict__ order, float* __restrict__ yw,
                      int* __restrict__ ssort) {
    int e = blockIdx.x * 256 + threadIdx.x;
    int r = recv[e];
    int p = atomicAdd(&cursors[r], 1);
    order[p] = e;
    ssort[p] = senders[e];

    float x = vec[e * 3 + 0], y = vec[e * 3 + 1], z = vec[e * 3 + 2];
    float nrm = sqrtf(x * x + y * y + z * z);
    float d = 1.f / (nrm + 1e-12f);
    x *= d; y *= d; z *= d;
    const float s3  = 1.7320508075688772f;
    const float s5  = 2.2360679774997896f;
    const float s15 = 3.8729833462074170f;
    const float c33 = 2.0916500663351889f;
    const float c32 = 10.246950765959598f;
    const float c31 = 1.6201851746019651f;
    const float c30 = 1.3228756555322954f;
    float x2 = x * x, y2 = y * y, z2 = z * z;
    float4 a, b, c, dd;
    a.x = s3 * y;  a.y = s3 * z;  a.z = s3 * x;
    a.w = s15 * x * y;
    b.x = s15 * y * z;
    b.y = 0.5f * s5 * (3.f * z2 - 1.f);
    b.z = s15 * x * z;
    b.w = 0.5f * s15 * (x2 - y2);
    c.x = c33 * y * (3.f * x2 - y2);
    c.y = c32 * x * y * z;
    c.z = c31 * y * (5.f * z2 - 1.f);
    c.w = c30 * z * (5.f * z2 - 3.f);
    dd.x = c31 * x * (5.f * z2 - 1.f);
    dd.y = 0.5f * c32 * z * (x2 - y2);
    dd.z = c33 * x * (x2 - 3.f * y2);
    dd.w = 0.f;
    float4* yp = reinterpret_cast<float4*>(yw + (size_t)p * 16);
    yp[0] = a; yp[1] = b; yp[2] = c; yp[3] = dd;
}

// ---------------- weight packing: fp32 W[K][N] -> B-frag-ordered bf16 hi/lo -----
// Read order in kmlp: slot = ((n*KS+s)*2+plane)*64 + lane; element t at ushort
// offset slot*8+t. B-frag (16x16x32): B[k = s*32 + (lane>>4)*8 + t][n*16 + (lane&15)].
__global__ void kpack(const float* __restrict__ W, int Kreal, int Ncols,
                      int KS, int NT, unsigned short* __restrict__ dst) {
    int idx = blockIdx.x * 256 + threadIdx.x;
    int total = NT * KS * 2 * 64;
    if (idx >= total) return;
    int lane  = idx & 63;
    int plane = (idx >> 6) & 1;
    int sn    = idx >> 7;               // n*KS + s
    int s = sn % KS, n = sn / KS;
    int g = lane >> 4, c = lane & 15;
    unsigned short out[8];
    #pragma unroll
    for (int t = 0; t < 8; ++t) {
        int k = s * 32 + g * 8 + t;
        float v = (k < Kreal) ? W[(size_t)k * Ncols + n * 16 + c] : 0.f;
        unsigned short hi = f2bf(v);
        out[t] = plane ? f2bf(v - bf2f(hi)) : hi;
    }
    uint4 o;
    o.x = (unsigned)out[0] | ((unsigned)out[1] << 16);
    o.y = (unsigned)out[2] | ((unsigned)out[3] << 16);
    o.z = (unsigned)out[4] | ((unsigned)out[5] << 16);
    o.w = (unsigned)out[6] | ((unsigned)out[7] << 16);
    *reinterpret_cast<uint4*>(dst + (size_t)idx * 8) = o;
}

// ---------------- MFMA split-bf16 4-layer MLP ----------------------------------
// Block = 256 thr = 4 waves; wave owns 16 edges (one 16x16x32 M-tile), fully
// barrier-free (all LDS regions wave-private). Activations stored in LDS in
// A-FRAGMENT ORDER, bf16 hi/lo planes, double-buffered (hA/hB). Weights read
// from packed global (lane-linear b128, no duplication). 3 MFMAs per product
// (Ah*Bh + Ah*Bl + Al*Bh) gives ~2^-16 relative error (fp32-grade).
// D layout [verified m89]: col = lane&15, row = (lane>>4)*4 + reg.
template<int NT, int KS, bool ACT, bool TOLDS>
__device__ __forceinline__ void mlayer(const unsigned short* __restrict__ wpk,
                                       const unsigned short* sh, const unsigned short* sl,
                                       unsigned short* dh, unsigned short* dl,
                                       float scale, float* __restrict__ gout, int lane) {
    const int g = lane >> 4, c = lane & 15;
    #pragma unroll
    for (int n = 0; n < NT; ++n) {
        f32x4 acc = {0.f, 0.f, 0.f, 0.f};
        #pragma unroll
        for (int s = 0; s < KS; ++s) {
            short8 ah = *reinterpret_cast<const short8*>(sh + (s * 64 + lane) * 8);
            short8 al = *reinterpret_cast<const short8*>(sl + (s * 64 + lane) * 8);
            short8 bh = *reinterpret_cast<const short8*>(
                wpk + (size_t)(((n * KS + s) * 2 + 0) * 64 + lane) * 8);
            short8 bl = *reinterpret_cast<const short8*>(
                wpk + (size_t)(((n * KS + s) * 2 + 1) * 64 + lane) * 8);
            acc = __builtin_amdgcn_mfma_f32_16x16x32_bf16(ah, bh, acc, 0, 0, 0);
            acc = __builtin_amdgcn_mfma_f32_16x16x32_bf16(ah, bl, acc, 0, 0, 0);
            acc = __builtin_amdgcn_mfma_f32_16x16x32_bf16(al, bh, acc, 0, 0, 0);
        }
        #pragma unroll
        for (int r = 0; r < 4; ++r) {
            float v = acc[r] * scale;
            if (ACT) v = silu(v);
            const int col = n * 16 + c;
            if (TOLDS) {
                // write into next layer's A-frag slot: lane' = ((col>>3)&3)*16+row,
                // s' = col>>5, t' = col&7, row = 4g+r
                unsigned short hi = f2bf(v);
                unsigned short lo = f2bf(v - bf2f(hi));
                int slot = (((col >> 5) * 64) + (((col >> 3) & 3) * 16) + g * 4 + r) * 8
                           + (col & 7);
                dh[slot] = hi;
                dl[slot] = lo;
            } else {
                gout[(size_t)(g * 4 + r) * 256 + col] = v;
            }
        }
    }
}

__global__ __launch_bounds__(256) void kmlp(const float* __restrict__ radial,
                                            const int* __restrict__ order,
                                            const unsigned short* __restrict__ wpk1,
                                            const unsigned short* __restrict__ wpk2,
                                            const unsigned short* __restrict__ wpk3,
                                            const unsigned short* __restrict__ wpk4,
                                            float* __restrict__ mix, int clo) {
    // per-wave LDS: radF(hi 512, lo 512) hA(1024,1024) hB(1024,1024) ushorts = 10 KB
    __shared__ __align__(16) unsigned short fr[4][5120];
    const int tid  = threadIdx.x;
    const int lane = tid & 63;
    const int wv   = tid >> 6;
    const int g    = lane >> 4;
    const int c    = lane & 15;
    unsigned short* radF_h = fr[wv];
    unsigned short* radF_l = fr[wv] + 512;
    unsigned short* hA_h   = fr[wv] + 1024;
    unsigned short* hA_l   = fr[wv] + 2048;
    unsigned short* hB_h   = fr[wv] + 3072;
    unsigned short* hB_l   = fr[wv] + 4096;

    const int tbase = blockIdx.x * 64 + wv * 16;   // chunk-relative edge base
    const int pb    = clo + tbase;                 // global permuted position

    // ---- stage radial A-frags (K padded 8->32; only g==0 holds real k)
    {
        float4 t0 = {0.f, 0.f, 0.f, 0.f}, t1 = {0.f, 0.f, 0.f, 0.f};
        if (g == 0) {
            const int eid = order[pb + c];
            const float* rp = radial + (size_t)eid * 8;
            t0 = *reinterpret_cast<const float4*>(rp);
            t1 = *reinterpret_cast<const float4*>(rp + 4);
        }
        float r8[8] = {t0.x, t0.y, t0.z, t0.w, t1.x, t1.y, t1.z, t1.w};
        #pragma unroll
        for (int t = 0; t < 8; ++t) {
            float v = (g == 0) ? r8[t] : 0.f;
            unsigned short hi = f2bf(v);
            radF_h[lane * 8 + t] = hi;
            radF_l[lane * 8 + t] = f2bf(v - bf2f(hi));
        }
    }
    asm volatile("" ::: "memory");

    // ---- layer 1: K=32(pad), N=64, silu(acc/sqrt8) -> hA
    mlayer<4, 1, true, true>(wpk1, radF_h, radF_l, hA_h, hA_l,
                             0.35355339059327373f, nullptr, lane);
    asm volatile("" ::: "memory");
    // ---- layer 2: 64->64 -> hB
    mlayer<4, 2, true, true>(wpk2, hA_h, hA_l, hB_h, hB_l, 0.125f, nullptr, lane);
    asm volatile("" ::: "memory");
    // ---- layer 3: 64->64 -> hA (old hA fully consumed by layer 2; same-wave order)
    mlayer<4, 2, true, true>(wpk3, hB_h, hB_l, hA_h, hA_l, 0.125f, nullptr, lane);
    asm volatile("" ::: "memory");
    // ---- layer 4: 64->256, no act -> mix
    mlayer<16, 2, false, false>(wpk4, hA_h, hA_l, nullptr, nullptr, 0.125f,
                                mix + (size_t)tbase * 256, lane);
}

// ---------------- per-node gather/accumulate (unchanged, known-good) ------------
__global__ __launch_bounds__(256) void kgather(const float* __restrict__ mix,
                                               const float* __restrict__ yw,
                                               const int* __restrict__ ssort,
                                               const float* __restrict__ node_feats,
                                               const int* __restrict__ offsets,
                                               const int* __restrict__ counts,
                                               float* __restrict__ out,
                                               int clo, int chi) {
    __shared__ float so[4][1024];
    const int lane = threadIdx.x & 63;
    const int wv   = threadIdx.x >> 6;
    const int n    = blockIdx.x * 4 + wv;

    const int start = offsets[n];
    const int cnt   = counts[n];
    const int end   = start + cnt;
    const int s0    = (start > clo) ? start : clo;
    const int s1    = (end < chi) ? end : chi;

    float a0 = 0.f;
    float a1[3] = {0.f, 0.f, 0.f};
    float a2[5] = {0.f, 0.f, 0.f, 0.f, 0.f};
    float a3[7] = {0.f, 0.f, 0.f, 0.f, 0.f, 0.f, 0.f};

    int i = s0;
    for (; i + 2 <= s1; i += 2) {
        const int sA = ssort[i];
        const int sB = ssort[i + 1];
        const float* mpA = mix + (size_t)(i - clo) * 256;
        const float* mpB = mpA + 256;
        const float fA = node_feats[sA * 64 + lane];
        const float fB = node_feats[sB * 64 + lane];
        const float4* ypA = reinterpret_cast<const float4*>(yw + (size_t)i * 16);
        const float4* ypB = ypA + 4;
        const float4 yaA = ypA[0], ybA = ypA[1], ycA = ypA[2], ydA = ypA[3];
        const float4 yaB = ypB[0], ybB = ypB[1], ycB = ypB[2], ydB = ypB[3];
        const float t0A = fA * mpA[lane],       t0B = fB * mpB[lane];
        const float t1A = fA * mpA[64 + lane],  t1B = fB * mpB[64 + lane];
        const float t2A = fA * mpA[128 + lane], t2B = fB * mpB[128 + lane];
        const float t3A = fA * mpA[192 + lane], t3B = fB * mpB[192 + lane];
        a0 += t0A + t0B;
        a1[0] += t1A * yaA.x + t1B * yaB.x;
        a1[1] += t1A * yaA.y + t1B * yaB.y;
        a1[2] += t1A * yaA.z + t1B * yaB.z;
        a2[0] += t2A * yaA.w + t2B * yaB.w;
        a2[1] += t2A * ybA.x + t2B * ybB.x;
        a2[2] += t2A * ybA.y + t2B * ybB.y;
        a2[3] += t2A * ybA.z + t2B * ybB.z;
        a2[4] += t2A * ybA.w + t2B * ybB.w;
        a3[0] += t3A * ycA.x + t3B * ycB.x;
        a3[1] += t3A * ycA.y + t3B * ycB.y;
        a3[2] += t3A * ycA.z + t3B * ycB.z;
        a3[3] += t3A * ycA.w + t3B * ycB.w;
        a3[4] += t3A * ydA.x + t3B * ydB.x;
        a3[5] += t3A * ydA.y + t3B * ydB.y;
        a3[6] += t3A * ydA.z + t3B * ydB.z;
    }
    if (i < s1) {
        const int sA = ssort[i];
        const float* mpA = mix + (size_t)(i - clo) * 256;
        const float fA = node_feats[sA * 64 + lane];
        const float4* ypA = reinterpret_cast<const float4*>(yw + (size_t)i * 16);
        const float4 yaA = ypA[0], ybA = ypA[1], ycA = ypA[2], ydA = ypA[3];
        const float t0A = fA * mpA[lane];
        const float t1A = fA * mpA[64 + lane];
        const float t2A = fA * mpA[128 + lane];
        const float t3A = fA * mpA[192 + lane];
        a0 += t0A;
        a1[0] += t1A * yaA.x; a1[1] += t1A * yaA.y; a1[2] += t1A * yaA.z;
        a2[0] += t2A * yaA.w; a2[1] += t2A * ybA.x; a2[2] += t2A * ybA.y;
        a2[3] += t2A * ybA.z; a2[4] += t2A * ybA.w;
        a3[0] += t3A * ycA.x; a3[1] += t3A * ycA.y; a3[2] += t3A * ycA.z;
        a3[3] += t3A * ycA.w; a3[4] += t3A * ydA.x; a3[5] += t3A * ydA.y;
        a3[6] += t3A * ydA.z;
    }

    so[wv][lane] = a0;
    #pragma unroll
    for (int j = 0; j < 3; ++j) so[wv][64  + lane * 3 + j] = a1[j];
    #pragma unroll
    for (int j = 0; j < 5; ++j) so[wv][256 + lane * 5 + j] = a2[j];
    #pragma unroll
    for (int j = 0; j < 7; ++j) so[wv][576 + lane * 7 + j] = a3[j];

    float* op = out + (size_t)n * 1024;
    if (start >= clo) {
        #pragma unroll
        for (int k = 0; k < 16; ++k)
            op[k * 64 + lane] = so[wv][k * 64 + lane] * 0.25f;
    } else if (s1 > s0) {
        #pragma unroll
        for (int k = 0; k < 16; ++k)
            op[k * 64 + lane] += so[wv][k * 64 + lane] * 0.25f;
    }
}

// ---------------- launch ----------------
extern "C" void kernel_launch(void* const* d_in, const int* in_sizes, int n_in,
                              void* d_out, int out_size, void* d_ws, size_t ws_size,
                              hipStream_t stream) {
    const float* vectors    = (const float*)d_in[0];
    const float* node_feats = (const float*)d_in[1];
    const float* radial     = (const float*)d_in[2];
    const float* w1         = (const float*)d_in[3];
    const float* w2         = (const float*)d_in[4];
    const float* w3         = (const float*)d_in[5];
    const float* w4         = (const float*)d_in[6];
    const int*   senders    = (const int*)d_in[7];
    const int*   receivers  = (const int*)d_in[8];
    float*       out        = (float*)d_out;

    char* ws = (char*)d_ws;
    int*   counts  = (int*)(ws);
    int*   offsets = (int*)(ws + OFF_OFFSETS);
    int*   cursors = (int*)(ws + OFF_CURSORS);
    int*   order   = (int*)(ws + OFF_ORDER);
    float* yw      = (float*)(ws + OFF_Y);
    int*   ssort   = (int*)(ws + OFF_SSORT);
    unsigned short* wpk1 = (unsigned short*)(ws + OFF_WPK1);
    unsigned short* wpk2 = (unsigned short*)(ws + OFF_WPK2);
    unsigned short* wpk3 = (unsigned short*)(ws + OFF_WPK3);
    unsigned short* wpk4 = (unsigned short*)(ws + OFF_WPK4);
    float* mix     = (float*)(ws + OFF_MIX);

    // adaptive mix chunking from ws_size (constant per session -> graph-safe)
    size_t avail = (ws_size > (size_t)OFF_MIX) ? ws_size - (size_t)OFF_MIX : 0;
    long maxE = (long)(avail / (256 * 4));
    maxE -= maxE % 64;
    if (maxE < 64) maxE = 64;
    if (maxE > N_EDGES) maxE = N_EDGES;
    const int nch = (int)((N_EDGES + maxE - 1) / maxE);

    hipMemsetAsync(counts, 0, N_NODES * sizeof(int), stream);
    if (nch > 1)
        hipMemsetAsync(out, 0, (size_t)out_size * sizeof(float), stream);
    khist <<<N_EDGES / 256, 256, 0, stream>>>(receivers, counts);
    kscan <<<1, 1024, 0, stream>>>(counts, offsets, cursors);
    kprep <<<N_EDGES / 256, 256, 0, stream>>>(vectors, senders, receivers, cursors,
                                              order, yw, ssort);
    // pack weights (re-done every call; ws is re-poisoned by harness)
    kpack <<<2,  256, 0, stream>>>(w1,  8,  64, 1,  4, wpk1);
    kpack <<<4,  256, 0, stream>>>(w2, 64,  64, 2,  4, wpk2);
    kpack <<<4,  256, 0, stream>>>(w3, 64,  64, 2,  4, wpk3);
    kpack <<<16, 256, 0, stream>>>(w4, 64, 256, 2, 16, wpk4);

    for (int ch = 0; ch < nch; ++ch) {
        const int clo = (int)((long)ch * maxE);
        const int chi = (int)(((long)clo + maxE < N_EDGES) ? clo + maxE : N_EDGES);
        kmlp   <<<(chi - clo) / 64, 256, 0, stream>>>(radial, order, wpk1, wpk2,
                                                      wpk3, wpk4, mix, clo);
        kgather<<<N_NODES / 4, 256, 0, stream>>>(mix, yw, ssort, node_feats,
                                                 offsets, counts, out, clo, chi);
    }
}